// Round 1
// baseline (1406.421 us; speedup 1.0000x reference)
//
#include <hip/hip_runtime.h>
#include <hip/hip_bf16.h>
#include <stdint.h>

// Problem constants
#define B_ROWS 32768
#define KTOT   3584   // 1024 + 512 + 2048 (concat of stream features)
#define NC     6144   // C panels: out_a|out_b|out_c|gate(3072)
#define OUT_N  1024

typedef unsigned short ushort_t;
typedef __attribute__((ext_vector_type(8))) short bf16x8;
typedef __attribute__((ext_vector_type(4))) float f32x4;

__device__ __forceinline__ float b2f(unsigned short u) {
    union { unsigned int i; float f; } x; x.i = ((unsigned int)u) << 16; return x.f;
}
__device__ __forceinline__ unsigned short f2b(float f) {
    union { float f; unsigned int i; } x; x.f = f;
    unsigned int r = x.i + 0x7fffu + ((x.i >> 16) & 1u);
    return (unsigned short)(r >> 16);
}

// async global->LDS, 16B per lane (CK-style addrspace casts)
__device__ __forceinline__ void gload_lds16(const void* g, void* l) {
    auto g1 = reinterpret_cast<const __attribute__((address_space(1))) char*>(
        reinterpret_cast<uintptr_t>(g));
    auto l3 = reinterpret_cast<__attribute__((address_space(3))) char*>(
        (uint32_t)reinterpret_cast<uintptr_t>(l));
    __builtin_amdgcn_global_load_lds(g1, l3, 16, 0, 0);
}

// ---------------------------------------------------------------------------
// Kernel 1: weight pack. WT[n][k] (bf16, 4096 x 3584). n<1024 -> W_s columns,
// n in [1024,4096) -> Wg_s columns. Rows of k are the concat of streams.
// ---------------------------------------------------------------------------
__global__ __launch_bounds__(256) void pack_wt_kernel(
    const float* __restrict__ Wa, const float* __restrict__ Wga,
    const float* __restrict__ Wb, const float* __restrict__ Wgb,
    const float* __restrict__ Wc, const float* __restrict__ Wgc,
    ushort_t* __restrict__ WT)
{
    int s = blockIdx.y;
    const float *Ws, *Wgs; int d, koff;
    if (s == 0)      { Ws = Wa; Wgs = Wga; d = 1024; koff = 0;    }
    else if (s == 1) { Ws = Wb; Wgs = Wgb; d = 512;  koff = 1024; }
    else             { Ws = Wc; Wgs = Wgc; d = 2048; koff = 1536; }
    int kt = blockIdx.x >> 6;          // k-tile (64 rows of source)
    int ntile = blockIdx.x & 63;       // n-tile (64 cols of 4096)
    if (kt >= (d >> 6)) return;
    int k0 = kt * 64, n0 = ntile * 64;
    const float* src; int ld, ncol0;
    if (n0 < 1024) { src = Ws;  ld = 1024; ncol0 = n0; }
    else           { src = Wgs; ld = 3072; ncol0 = n0 - 1024; }

    __shared__ float tile[64][65];
    int tx = threadIdx.x & 63, ty = threadIdx.x >> 6;
    for (int r = ty; r < 64; r += 4)
        tile[r][tx] = src[(size_t)(k0 + r) * ld + ncol0 + tx];
    __syncthreads();
    for (int r = ty; r < 64; r += 4)
        WT[(size_t)(n0 + r) * KTOT + koff + k0 + tx] = f2b(tile[tx][r]);
}

__global__ __launch_bounds__(256) void pack_bias_kernel(
    const float* __restrict__ ba, const float* __restrict__ bb, const float* __restrict__ bc,
    const float* __restrict__ bga, const float* __restrict__ bgb, const float* __restrict__ bgc,
    float* __restrict__ bias)
{
    int i = blockIdx.x * 256 + threadIdx.x;
    if (i >= NC) return;
    float v;
    if (i < 1024)      v = ba[i];
    else if (i < 2048) v = bb[i - 1024];
    else if (i < 3072) v = bc[i - 2048];
    else { int g = i - 3072; v = bga[g] + bgb[g] + bgc[g]; }
    bias[i] = v;
}

// ---------------------------------------------------------------------------
// Kernel 2: LayerNorm + ReLU + cast to bf16, writes F[32768][3584]
// ---------------------------------------------------------------------------
__global__ __launch_bounds__(256) void ln_relu_kernel(
    const float* __restrict__ xa, const float* __restrict__ xb, const float* __restrict__ xc,
    const float* __restrict__ wa, const float* __restrict__ wb, const float* __restrict__ wc,
    const float* __restrict__ ba, const float* __restrict__ bb, const float* __restrict__ bc,
    ushort_t* __restrict__ F)
{
    int row = blockIdx.x;
    int s = blockIdx.y;
    const float *x, *w, *b; int d, koff;
    if (s == 0)      { x = xa; w = wa; b = ba; d = 1024; koff = 0;    }
    else if (s == 1) { x = xb; w = wb; b = bb; d = 512;  koff = 1024; }
    else             { x = xc; w = wc; b = bc; d = 2048; koff = 1536; }
    const float* xr = x + (size_t)row * d;
    int tid = threadIdx.x;

    float s1 = 0.f, s2 = 0.f;
    for (int i = tid * 4; i < d; i += 1024) {
        float4 v = *(const float4*)(xr + i);
        s1 += v.x + v.y + v.z + v.w;
        s2 += v.x * v.x + v.y * v.y + v.z * v.z + v.w * v.w;
    }
    for (int o = 32; o > 0; o >>= 1) {
        s1 += __shfl_down(s1, o, 64);
        s2 += __shfl_down(s2, o, 64);
    }
    __shared__ float red1[4], red2[4], bcast[2];
    int wv = tid >> 6, ln = tid & 63;
    if (ln == 0) { red1[wv] = s1; red2[wv] = s2; }
    __syncthreads();
    if (tid == 0) {
        float t1 = red1[0] + red1[1] + red1[2] + red1[3];
        float t2 = red2[0] + red2[1] + red2[2] + red2[3];
        float mean = t1 / d;
        float var = t2 / d - mean * mean;
        bcast[0] = mean;
        bcast[1] = rsqrtf(var + 1e-5f);
    }
    __syncthreads();
    float mean = bcast[0], rstd = bcast[1];

    ushort_t* Fr = F + (size_t)row * KTOT + koff;
    for (int i = tid * 4; i < d; i += 1024) {
        float4 v  = *(const float4*)(xr + i);
        float4 wv4 = *(const float4*)(w + i);
        float4 bv4 = *(const float4*)(b + i);
        float o0 = fmaxf(0.f, (v.x - mean) * rstd * wv4.x + bv4.x);
        float o1 = fmaxf(0.f, (v.y - mean) * rstd * wv4.y + bv4.y);
        float o2 = fmaxf(0.f, (v.z - mean) * rstd * wv4.z + bv4.z);
        float o3 = fmaxf(0.f, (v.w - mean) * rstd * wv4.w + bv4.w);
        union { ushort_t u[4]; uint2 v2; } pk;
        pk.u[0] = f2b(o0); pk.u[1] = f2b(o1); pk.u[2] = f2b(o2); pk.u[3] = f2b(o3);
        *(uint2*)(Fr + i) = pk.v2;
    }
}

// ---------------------------------------------------------------------------
// Kernel 3: bf16 GEMM (m97 structure): 128x128 tile, BK=64, 4 waves,
// global_load_lds(16B) staging, mfma_f32_16x16x32_bf16.
// grid.y decodes 4 sub-GEMMs:
//   sub0: out_a  K=[0,1024)    N rows of WT [0,1024)     -> C cols [0,1024)
//   sub1: out_b  K=[1024,1536) N rows [0,1024)           -> C cols [1024,2048)
//   sub2: out_c  K=[1536,3584) N rows [0,1024)           -> C cols [2048,3072)
//   sub3: gate   K=[0,3584)    N rows [1024,4096)        -> C cols [3072,6144)
// ---------------------------------------------------------------------------
__global__ __launch_bounds__(256, 2) void gemm_kernel(
    const ushort_t* __restrict__ F, const ushort_t* __restrict__ WT,
    const float* __restrict__ bias, ushort_t* __restrict__ C)
{
    __shared__ ushort_t As[128 * 64];
    __shared__ ushort_t Bs[128 * 64];

    int y = blockIdx.y;
    int sub = (y < 24) ? (y >> 3) : 3;
    int nt  = (y < 24) ? (y & 7)  : (y - 24);
    int koff = (sub == 0) ? 0 : (sub == 1) ? 1024 : (sub == 2) ? 1536 : 0;
    int klen = (sub == 0) ? 1024 : (sub == 1) ? 512 : (sub == 2) ? 2048 : 3584;
    int wrow = (sub == 3) ? 1024 : 0;
    int row0 = blockIdx.x * 128;
    int n0 = wrow + nt * 128;
    int c0 = sub * 1024 + nt * 128;

    int tid = threadIdx.x, w = tid >> 6, l = tid & 63;

    const char* Ag = (const char*)(F  + (size_t)(row0 + w * 32 + (l >> 3)) * KTOT + koff) + (l & 7) * 16;
    const char* Bg = (const char*)(WT + (size_t)(n0   + w * 32 + (l >> 3)) * KTOT + koff) + (l & 7) * 16;
    ushort_t* Asw = &As[(w * 32) * 64];
    ushort_t* Bsw = &Bs[(w * 32) * 64];

    int wm0 = (w >> 1) * 64, wn0 = (w & 1) * 64;
    f32x4 acc[4][4];
    #pragma unroll
    for (int mi = 0; mi < 4; ++mi)
        #pragma unroll
        for (int ni = 0; ni < 4; ++ni)
            acc[mi][ni] = (f32x4){0.f, 0.f, 0.f, 0.f};

    int nkt = klen >> 6;
    for (int kt = 0; kt < nkt; ++kt) {
        __syncthreads();   // previous tile fully consumed
        const char* Akt = Ag + kt * 128;
        const char* Bkt = Bg + kt * 128;
        #pragma unroll
        for (int q = 0; q < 4; ++q) {
            gload_lds16(Akt + q * (8 * KTOT * 2), Asw + q * 8 * 64);
            gload_lds16(Bkt + q * (8 * KTOT * 2), Bsw + q * 8 * 64);
        }
        __syncthreads();   // compiler drains vmcnt(0) before barrier -> data ready
        #pragma unroll
        for (int ks = 0; ks < 2; ++ks) {
            bf16x8 af[4], bf[4];
            #pragma unroll
            for (int mi = 0; mi < 4; ++mi)
                af[mi] = *(const bf16x8*)&As[(wm0 + mi * 16 + (l & 15)) * 64 + ks * 32 + (l >> 4) * 8];
            #pragma unroll
            for (int ni = 0; ni < 4; ++ni)
                bf[ni] = *(const bf16x8*)&Bs[(wn0 + ni * 16 + (l & 15)) * 64 + ks * 32 + (l >> 4) * 8];
            #pragma unroll
            for (int mi = 0; mi < 4; ++mi)
                #pragma unroll
                for (int ni = 0; ni < 4; ++ni)
                    acc[mi][ni] = __builtin_amdgcn_mfma_f32_16x16x32_bf16(af[mi], bf[ni], acc[mi][ni], 0, 0, 0);
        }
    }

    // Epilogue: add bias, cast bf16, store into panel buffer C
    #pragma unroll
    for (int ni = 0; ni < 4; ++ni) {
        int col = c0 + wn0 + ni * 16 + (l & 15);
        float bv = bias[col];
        #pragma unroll
        for (int mi = 0; mi < 4; ++mi) {
            int rbase = row0 + wm0 + mi * 16 + (l >> 4) * 4;
            #pragma unroll
            for (int r = 0; r < 4; ++r)
                C[(size_t)(rbase + r) * NC + col] = f2b(acc[mi][ni][r] + bv);
        }
    }
}

// ---------------------------------------------------------------------------
// Kernel 4: gate softmax + weighted merge -> d_out (fp32)
// ---------------------------------------------------------------------------
typedef __attribute__((ext_vector_type(8))) unsigned short u16x8;

__global__ __launch_bounds__(256) void fuse_kernel(
    const ushort_t* __restrict__ C, float* __restrict__ out)
{
    int t = blockIdx.x * 256 + threadIdx.x;   // 32768*128 threads, 8 cols each
    int b  = t >> 7;
    int j0 = (t & 127) << 3;
    const ushort_t* Cr = C + (size_t)b * NC;
    u16x8 oa = *(const u16x8*)(Cr + j0);
    u16x8 ob = *(const u16x8*)(Cr + 1024 + j0);
    u16x8 oc = *(const u16x8*)(Cr + 2048 + j0);
    u16x8 g0 = *(const u16x8*)(Cr + 3072 + j0);
    u16x8 g1 = *(const u16x8*)(Cr + 4096 + j0);
    u16x8 g2 = *(const u16x8*)(Cr + 5120 + j0);
    float res[8];
    #pragma unroll
    for (int k = 0; k < 8; ++k) {
        float a0 = b2f(g0[k]), a1 = b2f(g1[k]), a2 = b2f(g2[k]);
        float m = fmaxf(a0, fmaxf(a1, a2));
        float e0 = __expf(a0 - m), e1 = __expf(a1 - m), e2 = __expf(a2 - m);
        float inv = 1.f / (e0 + e1 + e2);
        res[k] = (e0 * b2f(oa[k]) + e1 * b2f(ob[k]) + e2 * b2f(oc[k])) * inv;
    }
    float* op = out + (size_t)b * 1024 + j0;
    *(float4*)op       = (float4){res[0], res[1], res[2], res[3]};
    *(float4*)(op + 4) = (float4){res[4], res[5], res[6], res[7]};
}

// ---------------------------------------------------------------------------
extern "C" void kernel_launch(void* const* d_in, const int* in_sizes, int n_in,
                              void* d_out, int out_size, void* d_ws, size_t ws_size,
                              hipStream_t stream)
{
    const float* x_a   = (const float*)d_in[0];
    const float* lnw_a = (const float*)d_in[1];
    const float* lnb_a = (const float*)d_in[2];
    const float* W_a   = (const float*)d_in[3];
    const float* b_a   = (const float*)d_in[4];
    const float* Wg_a  = (const float*)d_in[5];
    const float* bg_a  = (const float*)d_in[6];
    const float* x_b   = (const float*)d_in[7];
    const float* lnw_b = (const float*)d_in[8];
    const float* lnb_b = (const float*)d_in[9];
    const float* W_b   = (const float*)d_in[10];
    const float* b_b   = (const float*)d_in[11];
    const float* Wg_b  = (const float*)d_in[12];
    const float* bg_b  = (const float*)d_in[13];
    const float* x_c   = (const float*)d_in[14];
    const float* lnw_c = (const float*)d_in[15];
    const float* lnb_c = (const float*)d_in[16];
    const float* W_c   = (const float*)d_in[17];
    const float* b_c   = (const float*)d_in[18];
    const float* Wg_c  = (const float*)d_in[19];
    const float* bg_c  = (const float*)d_in[20];

    // Workspace layout (total ~667 MB)
    char* ws = (char*)d_ws;
    ushort_t* F    = (ushort_t*)ws;                                   // 32768*3584*2 = 234,881,024
    ushort_t* WT   = (ushort_t*)(ws + 234881024);                     // 4096*3584*2  =  29,360,128
    ushort_t* Cbuf = (ushort_t*)(ws + 234881024 + 29360128);          // 32768*6144*2 = 402,653,184
    float*    bias = (float*)   (ws + 234881024 + 29360128 + 402653184); // 6144*4

    hipLaunchKernelGGL(pack_wt_kernel, dim3(2048, 3), dim3(256), 0, stream,
                       W_a, Wg_a, W_b, Wg_b, W_c, Wg_c, WT);
    hipLaunchKernelGGL(pack_bias_kernel, dim3(24), dim3(256), 0, stream,
                       b_a, b_b, b_c, bg_a, bg_b, bg_c, bias);
    hipLaunchKernelGGL(ln_relu_kernel, dim3(32768, 3), dim3(256), 0, stream,
                       x_a, x_b, x_c, lnw_a, lnw_b, lnw_c, lnb_a, lnb_b, lnb_c, F);
    hipLaunchKernelGGL(gemm_kernel, dim3(256, 48), dim3(256), 0, stream,
                       F, WT, bias, Cbuf);
    hipLaunchKernelGGL(fuse_kernel, dim3(16384), dim3(256), 0, stream,
                       Cbuf, (float*)d_out);
}

// Round 2
// 1099.109 us; speedup vs baseline: 1.2796x; 1.2796x over previous
//
#include <hip/hip_runtime.h>
#include <hip/hip_bf16.h>
#include <stdint.h>

// Problem constants
#define B_ROWS 32768
#define KTOT   3584   // 1024 + 512 + 2048 (concat of stream features)
#define NC     6144   // C panels: out_a|out_b|out_c|gate(3072)
#define OUT_N  1024

typedef unsigned short ushort_t;
typedef __attribute__((ext_vector_type(8))) short bf16x8;
typedef __attribute__((ext_vector_type(4))) float f32x4;

__device__ __forceinline__ float b2f(unsigned short u) {
    union { unsigned int i; float f; } x; x.i = ((unsigned int)u) << 16; return x.f;
}
__device__ __forceinline__ unsigned short f2b(float f) {
    union { float f; unsigned int i; } x; x.f = f;
    unsigned int r = x.i + 0x7fffu + ((x.i >> 16) & 1u);
    return (unsigned short)(r >> 16);
}

// async global->LDS, 16B per lane
__device__ __forceinline__ void gload_lds16(const void* g, void* l) {
    auto g1 = reinterpret_cast<const __attribute__((address_space(1))) char*>(
        reinterpret_cast<uintptr_t>(g));
    auto l3 = reinterpret_cast<__attribute__((address_space(3))) char*>(
        (uint32_t)reinterpret_cast<uintptr_t>(l));
    __builtin_amdgcn_global_load_lds(g1, l3, 16, 0, 0);
}

// ---------------------------------------------------------------------------
// Kernel 1: weight pack. WT[n][k] (bf16, 4096 x 3584).
// ---------------------------------------------------------------------------
__global__ __launch_bounds__(256) void pack_wt_kernel(
    const float* __restrict__ Wa, const float* __restrict__ Wga,
    const float* __restrict__ Wb, const float* __restrict__ Wgb,
    const float* __restrict__ Wc, const float* __restrict__ Wgc,
    ushort_t* __restrict__ WT)
{
    int s = blockIdx.y;
    const float *Ws, *Wgs; int d, koff;
    if (s == 0)      { Ws = Wa; Wgs = Wga; d = 1024; koff = 0;    }
    else if (s == 1) { Ws = Wb; Wgs = Wgb; d = 512;  koff = 1024; }
    else             { Ws = Wc; Wgs = Wgc; d = 2048; koff = 1536; }
    int kt = blockIdx.x >> 6;          // k-tile (64 rows of source)
    int ntile = blockIdx.x & 63;       // n-tile (64 cols of 4096)
    if (kt >= (d >> 6)) return;
    int k0 = kt * 64, n0 = ntile * 64;
    const float* src; int ld, ncol0;
    if (n0 < 1024) { src = Ws;  ld = 1024; ncol0 = n0; }
    else           { src = Wgs; ld = 3072; ncol0 = n0 - 1024; }

    __shared__ float tile[64][65];
    int tx = threadIdx.x & 63, ty = threadIdx.x >> 6;
    for (int r = ty; r < 64; r += 4)
        tile[r][tx] = src[(size_t)(k0 + r) * ld + ncol0 + tx];
    __syncthreads();
    for (int r = ty; r < 64; r += 4)
        WT[(size_t)(n0 + r) * KTOT + koff + k0 + tx] = f2b(tile[tx][r]);
}

__global__ __launch_bounds__(256) void pack_bias_kernel(
    const float* __restrict__ ba, const float* __restrict__ bb, const float* __restrict__ bc,
    const float* __restrict__ bga, const float* __restrict__ bgb, const float* __restrict__ bgc,
    float* __restrict__ bias)
{
    int i = blockIdx.x * 256 + threadIdx.x;
    if (i >= NC) return;
    float v;
    if (i < 1024)      v = ba[i];
    else if (i < 2048) v = bb[i - 1024];
    else if (i < 3072) v = bc[i - 2048];
    else { int g = i - 3072; v = bga[g] + bgb[g] + bgc[g]; }
    bias[i] = v;
}

// ---------------------------------------------------------------------------
// Kernel 2: LayerNorm + ReLU + cast to bf16, writes F[32768][3584]
// ---------------------------------------------------------------------------
__global__ __launch_bounds__(256) void ln_relu_kernel(
    const float* __restrict__ xa, const float* __restrict__ xb, const float* __restrict__ xc,
    const float* __restrict__ wa, const float* __restrict__ wb, const float* __restrict__ wc,
    const float* __restrict__ ba, const float* __restrict__ bb, const float* __restrict__ bc,
    ushort_t* __restrict__ F)
{
    int row = blockIdx.x;
    int s = blockIdx.y;
    const float *x, *w, *b; int d, koff;
    if (s == 0)      { x = xa; w = wa; b = ba; d = 1024; koff = 0;    }
    else if (s == 1) { x = xb; w = wb; b = bb; d = 512;  koff = 1024; }
    else             { x = xc; w = wc; b = bc; d = 2048; koff = 1536; }
    const float* xr = x + (size_t)row * d;
    int tid = threadIdx.x;

    float s1 = 0.f, s2 = 0.f;
    for (int i = tid * 4; i < d; i += 1024) {
        float4 v = *(const float4*)(xr + i);
        s1 += v.x + v.y + v.z + v.w;
        s2 += v.x * v.x + v.y * v.y + v.z * v.z + v.w * v.w;
    }
    for (int o = 32; o > 0; o >>= 1) {
        s1 += __shfl_down(s1, o, 64);
        s2 += __shfl_down(s2, o, 64);
    }
    __shared__ float red1[4], red2[4], bcast[2];
    int wv = tid >> 6, ln = tid & 63;
    if (ln == 0) { red1[wv] = s1; red2[wv] = s2; }
    __syncthreads();
    if (tid == 0) {
        float t1 = red1[0] + red1[1] + red1[2] + red1[3];
        float t2 = red2[0] + red2[1] + red2[2] + red2[3];
        float mean = t1 / d;
        float var = t2 / d - mean * mean;
        bcast[0] = mean;
        bcast[1] = rsqrtf(var + 1e-5f);
    }
    __syncthreads();
    float mean = bcast[0], rstd = bcast[1];

    ushort_t* Fr = F + (size_t)row * KTOT + koff;
    for (int i = tid * 4; i < d; i += 1024) {
        float4 v  = *(const float4*)(xr + i);
        float4 wv4 = *(const float4*)(w + i);
        float4 bv4 = *(const float4*)(b + i);
        float o0 = fmaxf(0.f, (v.x - mean) * rstd * wv4.x + bv4.x);
        float o1 = fmaxf(0.f, (v.y - mean) * rstd * wv4.y + bv4.y);
        float o2 = fmaxf(0.f, (v.z - mean) * rstd * wv4.z + bv4.z);
        float o3 = fmaxf(0.f, (v.w - mean) * rstd * wv4.w + bv4.w);
        union { ushort_t u[4]; uint2 v2; } pk;
        pk.u[0] = f2b(o0); pk.u[1] = f2b(o1); pk.u[2] = f2b(o2); pk.u[3] = f2b(o3);
        *(uint2*)(Fr + i) = pk.v2;
    }
}

// ---------------------------------------------------------------------------
// Kernel 3: bf16 GEMM, 256x256 tile, BK=64, 8 waves (2Mx4N), double-buffered
// 128KB LDS, distance-2 prefetch with counted vmcnt(8), raw s_barrier,
// XOR-swizzled LDS (pre-swizzled global source + swizzled ds_read), setprio.
//
// Flat grid of 3072 blocks; XCD-chunked order: xcd = bid%8 owns 16 row-panels,
// n-tile inner (24 n-tiles per row-panel) -> A-panel (1.75MB) L2-resident,
// WT (28MB) / F L3-resident.
// ---------------------------------------------------------------------------
__global__ __launch_bounds__(512, 2) void gemm_kernel(
    const ushort_t* __restrict__ F, const ushort_t* __restrict__ WT,
    const float* __restrict__ bias, ushort_t* __restrict__ C)
{
    extern __shared__ ushort_t lds_u16[];   // 131072 bytes
    char* lds = (char*)lds_u16;
    // buf layout (bytes): buf0 A @0 (32KB), buf0 B @32KB, buf1 A @64KB, buf1 B @96KB

    // ---- block decode (XCD-bijective: 3072 % 8 == 0) ----
    int bid = blockIdx.x;
    int newid = (bid & 7) * 384 + (bid >> 3);
    int rowpanel = newid / 24;             // 0..127
    int j = newid % 24;                    // n-tile
    int row0 = rowpanel * 256;
    int n0, koff, klen, c0;
    if (j < 4)       { n0 = j * 256;            koff = 0;    klen = 1024; c0 = j * 256; }
    else if (j < 8)  { n0 = (j - 4) * 256;      koff = 1024; klen = 512;  c0 = 1024 + (j - 4) * 256; }
    else if (j < 12) { n0 = (j - 8) * 256;      koff = 1536; klen = 2048; c0 = 2048 + (j - 8) * 256; }
    else             { n0 = 1024 + (j - 12) * 256; koff = 0; klen = 3584; c0 = 3072 + (j - 12) * 256; }

    int tid = threadIdx.x, w = tid >> 6, l = tid & 63;
    int wm0 = (w >> 2) * 128;   // wave M origin (2 waves)
    int wn0 = (w & 3) * 64;     // wave N origin (4 waves)

    // ---- staging addresses (source pre-swizzled so linear LDS dest == swizzled layout)
    // lane i of chunk covers row (chunk*8 + (i>>3)), 16B-slot (i&7) holding
    // global 16B-col (i&7)^(i>>3)  [row&7 == i>>3 since chunks are 8-row aligned]
    int srow = w * 32 + (l >> 3);                  // row for jj=0 (chunk = w*4)
    int scol = (((l & 7) ^ (l >> 3)) << 3);        // swizzled element col in [0,64)
    const ushort_t* Ag = F  + (size_t)(row0 + srow) * KTOT + koff + scol;
    const ushort_t* Bg = WT + (size_t)(n0   + srow) * KTOT + koff + scol;
    char* ldsAw = lds + (size_t)w * 4096;          // wave's 4 chunks x 1024B in A region

#define STAGE(bufsel, kt) do {                                              \
        const ushort_t* ag_ = Ag + (kt) * 64;                               \
        const ushort_t* bg_ = Bg + (kt) * 64;                               \
        char* la_ = ldsAw + (bufsel) * 65536;                               \
        _Pragma("unroll")                                                   \
        for (int jj = 0; jj < 4; ++jj) {                                    \
            gload_lds16(ag_ + jj * 8 * KTOT, la_ + jj * 1024);              \
            gload_lds16(bg_ + jj * 8 * KTOT, la_ + 32768 + jj * 1024);      \
        }                                                                   \
    } while (0)

    // ---- ds_read addresses (swizzled): frag (mi/ni, ks):
    // row = w?0 + idx*16 + (l&15); 16B-col = (ks*4 + (l>>4)) ^ (l&7)
    int rl = l & 15;
    int c16_0 = ((l >> 4)    ) ^ (l & 7);
    int c16_1 = ((l >> 4) + 4) ^ (l & 7);
    int aoff0 = (wm0 + rl) * 128 + c16_0 * 16;
    int aoff1 = (wm0 + rl) * 128 + c16_1 * 16;
    int boff0 = 32768 + (wn0 + rl) * 128 + c16_0 * 16;
    int boff1 = 32768 + (wn0 + rl) * 128 + c16_1 * 16;

    f32x4 acc[8][4];
    #pragma unroll
    for (int mi = 0; mi < 8; ++mi)
        #pragma unroll
        for (int ni = 0; ni < 4; ++ni)
            acc[mi][ni] = (f32x4){0.f, 0.f, 0.f, 0.f};

    int nkt = klen >> 6;   // 8..56, always >= 3

    // ---- prologue: stage tiles 0 and 1
    STAGE(0, 0);
    STAGE(1, 1);

#define TILE_BODY(CUR, VMCNT_ASM, DO_STAGE, TNEXT)                          \
    {                                                                       \
        asm volatile(VMCNT_ASM ::: "memory");                               \
        __builtin_amdgcn_s_barrier();                                       \
        const char* Ab_ = lds + (CUR) * 65536;                              \
        bf16x8 a0[8], a1[8], b0[4], b1[4];                                  \
        _Pragma("unroll")                                                   \
        for (int mi = 0; mi < 8; ++mi)                                      \
            a0[mi] = *(const bf16x8*)(Ab_ + aoff0 + mi * 2048);             \
        _Pragma("unroll")                                                   \
        for (int ni = 0; ni < 4; ++ni)                                      \
            b0[ni] = *(const bf16x8*)(Ab_ + boff0 + ni * 2048);             \
        _Pragma("unroll")                                                   \
        for (int mi = 0; mi < 8; ++mi)                                      \
            a1[mi] = *(const bf16x8*)(Ab_ + aoff1 + mi * 2048);             \
        _Pragma("unroll")                                                   \
        for (int ni = 0; ni < 4; ++ni)                                      \
            b1[ni] = *(const bf16x8*)(Ab_ + boff1 + ni * 2048);             \
        __builtin_amdgcn_s_setprio(1);                                      \
        _Pragma("unroll")                                                   \
        for (int mi = 0; mi < 8; ++mi)                                      \
            _Pragma("unroll")                                               \
            for (int ni = 0; ni < 4; ++ni)                                  \
                acc[mi][ni] = __builtin_amdgcn_mfma_f32_16x16x32_bf16(      \
                    a0[mi], b0[ni], acc[mi][ni], 0, 0, 0);                  \
        __builtin_amdgcn_s_setprio(0);                                      \
        asm volatile("s_waitcnt lgkmcnt(0)" ::: "memory");                  \
        __builtin_amdgcn_s_barrier();                                       \
        if (DO_STAGE) STAGE(CUR, TNEXT);                                    \
        __builtin_amdgcn_s_setprio(1);                                      \
        _Pragma("unroll")                                                   \
        for (int mi = 0; mi < 8; ++mi)                                      \
            _Pragma("unroll")                                               \
            for (int ni = 0; ni < 4; ++ni)                                  \
                acc[mi][ni] = __builtin_amdgcn_mfma_f32_16x16x32_bf16(      \
                    a1[mi], b1[ni], acc[mi][ni], 0, 0, 0);                  \
        __builtin_amdgcn_s_setprio(0);                                      \
    }

    // main loop: tiles 0..nkt-2 with vmcnt(8) (tile t landed, t+1 in flight)
    for (int t = 0; t < nkt - 1; ++t) {
        int cur = t & 1;
        TILE_BODY(cur, "s_waitcnt vmcnt(8)", (t + 2 < nkt), t + 2)
    }
    // last tile: drain everything
    {
        int cur = (nkt - 1) & 1;
        TILE_BODY(cur, "s_waitcnt vmcnt(0)", false, 0)
    }
#undef TILE_BODY
#undef STAGE

    // ---- epilogue: bias + bf16 cast + store
    #pragma unroll
    for (int ni = 0; ni < 4; ++ni) {
        int col = c0 + wn0 + ni * 16 + rl;
        float bv = bias[col];
        #pragma unroll
        for (int mi = 0; mi < 8; ++mi) {
            int rbase = row0 + wm0 + mi * 16 + (l >> 4) * 4;
            #pragma unroll
            for (int r = 0; r < 4; ++r)
                C[(size_t)(rbase + r) * NC + col] = f2b(acc[mi][ni][r] + bv);
        }
    }
}

// ---------------------------------------------------------------------------
// Kernel 4: gate softmax + weighted merge -> d_out (fp32)
// ---------------------------------------------------------------------------
typedef __attribute__((ext_vector_type(8))) unsigned short u16x8;

__global__ __launch_bounds__(256) void fuse_kernel(
    const ushort_t* __restrict__ C, float* __restrict__ out)
{
    int t = blockIdx.x * 256 + threadIdx.x;   // 32768*128 threads, 8 cols each
    int b  = t >> 7;
    int j0 = (t & 127) << 3;
    const ushort_t* Cr = C + (size_t)b * NC;
    u16x8 oa = *(const u16x8*)(Cr + j0);
    u16x8 ob = *(const u16x8*)(Cr + 1024 + j0);
    u16x8 oc = *(const u16x8*)(Cr + 2048 + j0);
    u16x8 g0 = *(const u16x8*)(Cr + 3072 + j0);
    u16x8 g1 = *(const u16x8*)(Cr + 4096 + j0);
    u16x8 g2 = *(const u16x8*)(Cr + 5120 + j0);
    float res[8];
    #pragma unroll
    for (int k = 0; k < 8; ++k) {
        float a0 = b2f(g0[k]), a1 = b2f(g1[k]), a2 = b2f(g2[k]);
        float m = fmaxf(a0, fmaxf(a1, a2));
        float e0 = __expf(a0 - m), e1 = __expf(a1 - m), e2 = __expf(a2 - m);
        float inv = 1.f / (e0 + e1 + e2);
        res[k] = (e0 * b2f(oa[k]) + e1 * b2f(ob[k]) + e2 * b2f(oc[k])) * inv;
    }
    float* op = out + (size_t)b * 1024 + j0;
    *(float4*)op       = (float4){res[0], res[1], res[2], res[3]};
    *(float4*)(op + 4) = (float4){res[4], res[5], res[6], res[7]};
}

// ---------------------------------------------------------------------------
extern "C" void kernel_launch(void* const* d_in, const int* in_sizes, int n_in,
                              void* d_out, int out_size, void* d_ws, size_t ws_size,
                              hipStream_t stream)
{
    const float* x_a   = (const float*)d_in[0];
    const float* lnw_a = (const float*)d_in[1];
    const float* lnb_a = (const float*)d_in[2];
    const float* W_a   = (const float*)d_in[3];
    const float* b_a   = (const float*)d_in[4];
    const float* Wg_a  = (const float*)d_in[5];
    const float* bg_a  = (const float*)d_in[6];
    const float* x_b   = (const float*)d_in[7];
    const float* lnw_b = (const float*)d_in[8];
    const float* lnb_b = (const float*)d_in[9];
    const float* W_b   = (const float*)d_in[10];
    const float* b_b   = (const float*)d_in[11];
    const float* Wg_b  = (const float*)d_in[12];
    const float* bg_b  = (const float*)d_in[13];
    const float* x_c   = (const float*)d_in[14];
    const float* lnw_c = (const float*)d_in[15];
    const float* lnb_c = (const float*)d_in[16];
    const float* W_c   = (const float*)d_in[17];
    const float* b_c   = (const float*)d_in[18];
    const float* Wg_c  = (const float*)d_in[19];
    const float* bg_c  = (const float*)d_in[20];

    // Workspace layout (total ~667 MB)
    char* ws = (char*)d_ws;
    ushort_t* F    = (ushort_t*)ws;                                   // 32768*3584*2
    ushort_t* WT   = (ushort_t*)(ws + 234881024);                     // 4096*3584*2
    ushort_t* Cbuf = (ushort_t*)(ws + 234881024 + 29360128);          // 32768*6144*2
    float*    bias = (float*)   (ws + 234881024 + 29360128 + 402653184); // 6144*4

    hipLaunchKernelGGL(pack_wt_kernel, dim3(2048, 3), dim3(256), 0, stream,
                       W_a, Wg_a, W_b, Wg_b, W_c, Wg_c, WT);
    hipLaunchKernelGGL(pack_bias_kernel, dim3(24), dim3(256), 0, stream,
                       b_a, b_b, b_c, bg_a, bg_b, bg_c, bias);
    hipLaunchKernelGGL(ln_relu_kernel, dim3(32768, 3), dim3(256), 0, stream,
                       x_a, x_b, x_c, lnw_a, lnw_b, lnw_c, lnb_a, lnb_b, lnb_c, F);
    hipLaunchKernelGGL(gemm_kernel, dim3(3072), dim3(512), 131072, stream,
                       F, WT, bias, Cbuf);
    hipLaunchKernelGGL(fuse_kernel, dim3(16384), dim3(256), 0, stream,
                       Cbuf, (float*)d_out);
}

// Round 3
// 1080.572 us; speedup vs baseline: 1.3016x; 1.0172x over previous
//
#include <hip/hip_runtime.h>
#include <hip/hip_bf16.h>
#include <stdint.h>

// Problem constants
#define B_ROWS 32768
#define KTOT   3584   // 1024 + 512 + 2048 (concat of stream features)
#define NC     6144   // C panels: out_a|out_b|out_c|gate(3072)
#define OUT_N  1024

typedef unsigned short ushort_t;
typedef __attribute__((ext_vector_type(8))) short bf16x8;
typedef __attribute__((ext_vector_type(4))) float f32x4;

__device__ __forceinline__ float b2f(unsigned short u) {
    union { unsigned int i; float f; } x; x.i = ((unsigned int)u) << 16; return x.f;
}
__device__ __forceinline__ unsigned short f2b(float f) {
    union { float f; unsigned int i; } x; x.f = f;
    unsigned int r = x.i + 0x7fffu + ((x.i >> 16) & 1u);
    return (unsigned short)(r >> 16);
}

// async global->LDS, 16B per lane
__device__ __forceinline__ void gload_lds16(const void* g, void* l) {
    auto g1 = reinterpret_cast<const __attribute__((address_space(1))) char*>(
        reinterpret_cast<uintptr_t>(g));
    auto l3 = reinterpret_cast<__attribute__((address_space(3))) char*>(
        (uint32_t)reinterpret_cast<uintptr_t>(l));
    __builtin_amdgcn_global_load_lds(g1, l3, 16, 0, 0);
}

// ds_read_b128 with compile-time offset (keeps addr-VALU off the hot path)
template<int OFF>
__device__ __forceinline__ bf16x8 dsr(uint32_t addr) {
    bf16x8 d;
    asm volatile("ds_read_b128 %0, %1 offset:%2" : "=v"(d) : "v"(addr), "i"(OFF));
    return d;
}

// ---------------------------------------------------------------------------
// Kernel 1: weight pack. WT[n][k] (bf16, 4096 x 3584).
// ---------------------------------------------------------------------------
__global__ __launch_bounds__(256) void pack_wt_kernel(
    const float* __restrict__ Wa, const float* __restrict__ Wga,
    const float* __restrict__ Wb, const float* __restrict__ Wgb,
    const float* __restrict__ Wc, const float* __restrict__ Wgc,
    ushort_t* __restrict__ WT)
{
    int s = blockIdx.y;
    const float *Ws, *Wgs; int d, koff;
    if (s == 0)      { Ws = Wa; Wgs = Wga; d = 1024; koff = 0;    }
    else if (s == 1) { Ws = Wb; Wgs = Wgb; d = 512;  koff = 1024; }
    else             { Ws = Wc; Wgs = Wgc; d = 2048; koff = 1536; }
    int kt = blockIdx.x >> 6;
    int ntile = blockIdx.x & 63;
    if (kt >= (d >> 6)) return;
    int k0 = kt * 64, n0 = ntile * 64;
    const float* src; int ld, ncol0;
    if (n0 < 1024) { src = Ws;  ld = 1024; ncol0 = n0; }
    else           { src = Wgs; ld = 3072; ncol0 = n0 - 1024; }

    __shared__ float tile[64][65];
    int tx = threadIdx.x & 63, ty = threadIdx.x >> 6;
    for (int r = ty; r < 64; r += 4)
        tile[r][tx] = src[(size_t)(k0 + r) * ld + ncol0 + tx];
    __syncthreads();
    for (int r = ty; r < 64; r += 4)
        WT[(size_t)(n0 + r) * KTOT + koff + k0 + tx] = f2b(tile[tx][r]);
}

__global__ __launch_bounds__(256) void pack_bias_kernel(
    const float* __restrict__ ba, const float* __restrict__ bb, const float* __restrict__ bc,
    const float* __restrict__ bga, const float* __restrict__ bgb, const float* __restrict__ bgc,
    float* __restrict__ bias)
{
    int i = blockIdx.x * 256 + threadIdx.x;
    if (i >= NC) return;
    float v;
    if (i < 1024)      v = ba[i];
    else if (i < 2048) v = bb[i - 1024];
    else if (i < 3072) v = bc[i - 2048];
    else { int g = i - 3072; v = bga[g] + bgb[g] + bgc[g]; }
    bias[i] = v;
}

// ---------------------------------------------------------------------------
// Kernel 2: LayerNorm + ReLU + cast to bf16, writes F[32768][3584]
// ---------------------------------------------------------------------------
__global__ __launch_bounds__(256) void ln_relu_kernel(
    const float* __restrict__ xa, const float* __restrict__ xb, const float* __restrict__ xc,
    const float* __restrict__ wa, const float* __restrict__ wb, const float* __restrict__ wc,
    const float* __restrict__ ba, const float* __restrict__ bb, const float* __restrict__ bc,
    ushort_t* __restrict__ F)
{
    int row = blockIdx.x;
    int s = blockIdx.y;
    const float *x, *w, *b; int d, koff;
    if (s == 0)      { x = xa; w = wa; b = ba; d = 1024; koff = 0;    }
    else if (s == 1) { x = xb; w = wb; b = bb; d = 512;  koff = 1024; }
    else             { x = xc; w = wc; b = bc; d = 2048; koff = 1536; }
    const float* xr = x + (size_t)row * d;
    int tid = threadIdx.x;

    float s1 = 0.f, s2 = 0.f;
    for (int i = tid * 4; i < d; i += 1024) {
        float4 v = *(const float4*)(xr + i);
        s1 += v.x + v.y + v.z + v.w;
        s2 += v.x * v.x + v.y * v.y + v.z * v.z + v.w * v.w;
    }
    for (int o = 32; o > 0; o >>= 1) {
        s1 += __shfl_down(s1, o, 64);
        s2 += __shfl_down(s2, o, 64);
    }
    __shared__ float red1[4], red2[4], bcast[2];
    int wv = tid >> 6, ln = tid & 63;
    if (ln == 0) { red1[wv] = s1; red2[wv] = s2; }
    __syncthreads();
    if (tid == 0) {
        float t1 = red1[0] + red1[1] + red1[2] + red1[3];
        float t2 = red2[0] + red2[1] + red2[2] + red2[3];
        float mean = t1 / d;
        float var = t2 / d - mean * mean;
        bcast[0] = mean;
        bcast[1] = rsqrtf(var + 1e-5f);
    }
    __syncthreads();
    float mean = bcast[0], rstd = bcast[1];

    ushort_t* Fr = F + (size_t)row * KTOT + koff;
    for (int i = tid * 4; i < d; i += 1024) {
        float4 v  = *(const float4*)(xr + i);
        float4 wv4 = *(const float4*)(w + i);
        float4 bv4 = *(const float4*)(b + i);
        float o0 = fmaxf(0.f, (v.x - mean) * rstd * wv4.x + bv4.x);
        float o1 = fmaxf(0.f, (v.y - mean) * rstd * wv4.y + bv4.y);
        float o2 = fmaxf(0.f, (v.z - mean) * rstd * wv4.z + bv4.z);
        float o3 = fmaxf(0.f, (v.w - mean) * rstd * wv4.w + bv4.w);
        union { ushort_t u[4]; uint2 v2; } pk;
        pk.u[0] = f2b(o0); pk.u[1] = f2b(o1); pk.u[2] = f2b(o2); pk.u[3] = f2b(o3);
        *(uint2*)(Fr + i) = pk.v2;
    }
}

// ---------------------------------------------------------------------------
// Kernel 3: bf16 GEMM, 256x256 tile, BK=64, 8 waves (2Mx4N), dbuf 128KB LDS.
// 8-phase schedule (4 quadrant-phases per K-tile): per phase
//   {ds_read subtile ; stage 1 half-tile ; s_barrier ; lgkmcnt(0)+sched_barrier ;
//    setprio(1) ; 16 MFMA ; setprio(0) ; s_barrier}
// vmcnt(2) once per K-tile (tile t fully landed; only T(t+1).h0 outstanding).
// Staging: T(t+1).h1/h2/h3 in Q0/Q1/Q2 -> buf[nxt]; T(t+2).h0 in Q3 -> buf[cur]
// (safe: buf[cur] reads all retired by Q2's lgkmcnt(0)+barrier).
// ---------------------------------------------------------------------------
__global__ __launch_bounds__(512, 2) void gemm_kernel(
    const ushort_t* __restrict__ F, const ushort_t* __restrict__ WT,
    const float* __restrict__ bias, ushort_t* __restrict__ C)
{
    extern __shared__ ushort_t lds_u16[];   // 131072 bytes
    // byte layout: buf0 A @0 (32KB), buf0 B @32KB, buf1 A @64KB, buf1 B @96KB

    // ---- block decode (XCD-bijective: 3072 % 8 == 0) ----
    int bid = blockIdx.x;
    int newid = (bid & 7) * 384 + (bid >> 3);
    int rowpanel = newid / 24;             // 0..127
    int j = newid % 24;                    // n-tile
    int row0 = rowpanel * 256;
    int n0, koff, klen, c0;
    if (j < 4)       { n0 = j * 256;            koff = 0;    klen = 1024; c0 = j * 256; }
    else if (j < 8)  { n0 = (j - 4) * 256;      koff = 1024; klen = 512;  c0 = 1024 + (j - 4) * 256; }
    else if (j < 12) { n0 = (j - 8) * 256;      koff = 1536; klen = 2048; c0 = 2048 + (j - 8) * 256; }
    else             { n0 = 1024 + (j - 12) * 256; koff = 0; klen = 3584; c0 = 3072 + (j - 12) * 256; }

    int tid = threadIdx.x, w = tid >> 6, l = tid & 63;
    int wm0 = (w >> 2) * 128;   // wave M origin (2 M-waves)
    int wn0 = (w & 3) * 64;     // wave N origin (4 N-waves)

    // ---- staging source (pre-swizzled so linear LDS dest == swizzled layout)
    int srow = w * 32 + (l >> 3);                  // row for jj=0
    int scol = (((l & 7) ^ (l >> 3)) << 3);        // swizzled element col in [0,64)
    const ushort_t* Ag = F  + (size_t)(row0 + srow) * KTOT + koff + scol;
    const ushort_t* Bg = WT + (size_t)(n0   + srow) * KTOT + koff + scol;

    uint32_t lds_base = (uint32_t)(uintptr_t)lds_u16;
    uint32_t ldsStA = lds_base + (uint32_t)w * 4096u;  // wave's A stage base

#define STG_A(SELOFF, kt, JJ0) do {                                              \
        gload_lds16(Ag + (size_t)(kt) * 64 + (size_t)(JJ0) * 8 * KTOT,           \
                    (void*)(uintptr_t)(ldsStA + (SELOFF) + (JJ0) * 1024u));      \
        gload_lds16(Ag + (size_t)(kt) * 64 + (size_t)((JJ0) + 1) * 8 * KTOT,     \
                    (void*)(uintptr_t)(ldsStA + (SELOFF) + ((JJ0) + 1) * 1024u)); } while (0)
#define STG_B(SELOFF, kt, JJ0) do {                                              \
        gload_lds16(Bg + (size_t)(kt) * 64 + (size_t)(JJ0) * 8 * KTOT,           \
                    (void*)(uintptr_t)(ldsStA + 32768u + (SELOFF) + (JJ0) * 1024u)); \
        gload_lds16(Bg + (size_t)(kt) * 64 + (size_t)((JJ0) + 1) * 8 * KTOT,     \
                    (void*)(uintptr_t)(ldsStA + 32768u + (SELOFF) + ((JJ0) + 1) * 1024u)); } while (0)

    // ---- ds_read base addrs (swizzled): 16B-col = (ks*4 + (l>>4)) ^ (l&7)
    int rl = l & 15;
    int c16_0 = ((l >> 4)    ) ^ (l & 7);
    int c16_1 = ((l >> 4) + 4) ^ (l & 7);
    uint32_t aA0 = lds_base + (uint32_t)((wm0 + rl) * 128 + c16_0 * 16);
    uint32_t aA1 = lds_base + (uint32_t)((wm0 + rl) * 128 + c16_1 * 16);
    uint32_t aB0 = lds_base + 32768u + (uint32_t)((wn0 + rl) * 128 + c16_0 * 16);
    uint32_t aB1 = lds_base + 32768u + (uint32_t)((wn0 + rl) * 128 + c16_1 * 16);

#define R_A4(dst, base, MI0) do {                          \
        dst[0] = dsr<((MI0)+0)*2048>(base);                \
        dst[1] = dsr<((MI0)+1)*2048>(base);                \
        dst[2] = dsr<((MI0)+2)*2048>(base);                \
        dst[3] = dsr<((MI0)+3)*2048>(base); } while (0)
#define R_B2(dst, base, NI0) do {                          \
        dst[0] = dsr<((NI0)+0)*2048>(base);                \
        dst[1] = dsr<((NI0)+1)*2048>(base); } while (0)

#define MFMA_Q(Aks0, Aks1, Bks0, Bks1, MI0, NI0) do {                            \
        _Pragma("unroll")                                                        \
        for (int mi = 0; mi < 4; ++mi)                                           \
            _Pragma("unroll")                                                    \
            for (int ni = 0; ni < 2; ++ni)                                       \
                acc[(MI0)+mi][(NI0)+ni] = __builtin_amdgcn_mfma_f32_16x16x32_bf16( \
                    Aks0[mi], Bks0[ni], acc[(MI0)+mi][(NI0)+ni], 0, 0, 0);       \
        _Pragma("unroll")                                                        \
        for (int mi = 0; mi < 4; ++mi)                                           \
            _Pragma("unroll")                                                    \
            for (int ni = 0; ni < 2; ++ni)                                       \
                acc[(MI0)+mi][(NI0)+ni] = __builtin_amdgcn_mfma_f32_16x16x32_bf16( \
                    Aks1[mi], Bks1[ni], acc[(MI0)+mi][(NI0)+ni], 0, 0, 0);       \
        } while (0)

    f32x4 acc[8][4];
    #pragma unroll
    for (int mi = 0; mi < 8; ++mi)
        #pragma unroll
        for (int ni = 0; ni < 4; ++ni)
            acc[mi][ni] = (f32x4){0.f, 0.f, 0.f, 0.f};

    int nkt = klen >> 6;   // 8..56

    // ---- prologue: T0 h0..h3 -> buf0, T1.h0 -> buf1 (issue order matters)
    STG_A(0u, 0, 0); STG_A(0u, 0, 2); STG_B(0u, 0, 0); STG_B(0u, 0, 2);
    STG_A(65536u, 1, 0);

    for (int t = 0; t < nkt; ++t) {
        const uint32_t co  = (t & 1) ? 65536u : 0u;
        const uint32_t no_ = co ^ 65536u;
        int t1 = (t + 1 < nkt) ? t + 1 : nkt - 1;
        int t2 = (t + 2 < nkt) ? t + 2 : nkt - 1;

        asm volatile("s_waitcnt vmcnt(2)" ::: "memory");   // tile t fully landed
        __builtin_amdgcn_s_barrier();

        bf16x8 alo0[4], alo1[4], ahi0[4], ahi1[4];
        bf16x8 blo0[2], blo1[2], bhi0[2], bhi1[2];

        // ---- Q0: (m-lo, n-lo)
        R_A4(alo0, aA0 + co, 0); R_A4(alo1, aA1 + co, 0);
        R_B2(blo0, aB0 + co, 0); R_B2(blo1, aB1 + co, 0);
        STG_A(no_, t1, 2);                                 // T(t+1).h1
        __builtin_amdgcn_s_barrier();
        asm volatile("s_waitcnt lgkmcnt(0)" ::: "memory");
        __builtin_amdgcn_sched_barrier(0);
        __builtin_amdgcn_s_setprio(1);
        MFMA_Q(alo0, alo1, blo0, blo1, 0, 0);
        __builtin_amdgcn_s_setprio(0);
        __builtin_amdgcn_s_barrier();

        // ---- Q1: (m-lo, n-hi)
        R_B2(bhi0, aB0 + co, 2); R_B2(bhi1, aB1 + co, 2);
        STG_B(no_, t1, 0);                                 // T(t+1).h2
        __builtin_amdgcn_s_barrier();
        asm volatile("s_waitcnt lgkmcnt(0)" ::: "memory");
        __builtin_amdgcn_sched_barrier(0);
        __builtin_amdgcn_s_setprio(1);
        MFMA_Q(alo0, alo1, bhi0, bhi1, 0, 2);
        __builtin_amdgcn_s_setprio(0);
        __builtin_amdgcn_s_barrier();

        // ---- Q2: (m-hi, n-lo)
        R_A4(ahi0, aA0 + co, 4); R_A4(ahi1, aA1 + co, 4);
        STG_B(no_, t1, 2);                                 // T(t+1).h3
        __builtin_amdgcn_s_barrier();
        asm volatile("s_waitcnt lgkmcnt(0)" ::: "memory");
        __builtin_amdgcn_sched_barrier(0);
        __builtin_amdgcn_s_setprio(1);
        MFMA_Q(ahi0, ahi1, blo0, blo1, 4, 0);
        __builtin_amdgcn_s_setprio(0);
        __builtin_amdgcn_s_barrier();

        // ---- Q3: (m-hi, n-hi) — all buf[cur] reads retired; stage into cur
        STG_A(co, t2, 0);                                  // T(t+2).h0
        __builtin_amdgcn_s_barrier();
        __builtin_amdgcn_s_setprio(1);
        MFMA_Q(ahi0, ahi1, bhi0, bhi1, 4, 2);
        __builtin_amdgcn_s_setprio(0);
        // next iteration: vmcnt(2) + barrier
    }

#undef STG_A
#undef STG_B
#undef R_A4
#undef R_B2
#undef MFMA_Q

    // ---- epilogue: bias + bf16 cast + store
    #pragma unroll
    for (int ni = 0; ni < 4; ++ni) {
        int col = c0 + wn0 + ni * 16 + rl;
        float bv = bias[col];
        #pragma unroll
        for (int mi = 0; mi < 8; ++mi) {
            int rbase = row0 + wm0 + mi * 16 + (l >> 4) * 4;
            #pragma unroll
            for (int r = 0; r < 4; ++r)
                C[(size_t)(rbase + r) * NC + col] = f2b(acc[mi][ni][r] + bv);
        }
    }
}

// ---------------------------------------------------------------------------
// Kernel 4: gate softmax + weighted merge -> d_out (fp32)
// ---------------------------------------------------------------------------
typedef __attribute__((ext_vector_type(8))) unsigned short u16x8;

__global__ __launch_bounds__(256) void fuse_kernel(
    const ushort_t* __restrict__ C, float* __restrict__ out)
{
    int t = blockIdx.x * 256 + threadIdx.x;
    int b  = t >> 7;
    int j0 = (t & 127) << 3;
    const ushort_t* Cr = C + (size_t)b * NC;
    u16x8 oa = *(const u16x8*)(Cr + j0);
    u16x8 ob = *(const u16x8*)(Cr + 1024 + j0);
    u16x8 oc = *(const u16x8*)(Cr + 2048 + j0);
    u16x8 g0 = *(const u16x8*)(Cr + 3072 + j0);
    u16x8 g1 = *(const u16x8*)(Cr + 4096 + j0);
    u16x8 g2 = *(const u16x8*)(Cr + 5120 + j0);
    float res[8];
    #pragma unroll
    for (int k = 0; k < 8; ++k) {
        float a0 = b2f(g0[k]), a1 = b2f(g1[k]), a2 = b2f(g2[k]);
        float m = fmaxf(a0, fmaxf(a1, a2));
        float e0 = __expf(a0 - m), e1 = __expf(a1 - m), e2 = __expf(a2 - m);
        float inv = 1.f / (e0 + e1 + e2);
        res[k] = (e0 * b2f(oa[k]) + e1 * b2f(ob[k]) + e2 * b2f(oc[k])) * inv;
    }
    float* op = out + (size_t)b * 1024 + j0;
    *(float4*)op       = (float4){res[0], res[1], res[2], res[3]};
    *(float4*)(op + 4) = (float4){res[4], res[5], res[6], res[7]};
}

// ---------------------------------------------------------------------------
extern "C" void kernel_launch(void* const* d_in, const int* in_sizes, int n_in,
                              void* d_out, int out_size, void* d_ws, size_t ws_size,
                              hipStream_t stream)
{
    const float* x_a   = (const float*)d_in[0];
    const float* lnw_a = (const float*)d_in[1];
    const float* lnb_a = (const float*)d_in[2];
    const float* W_a   = (const float*)d_in[3];
    const float* b_a   = (const float*)d_in[4];
    const float* Wg_a  = (const float*)d_in[5];
    const float* bg_a  = (const float*)d_in[6];
    const float* x_b   = (const float*)d_in[7];
    const float* lnw_b = (const float*)d_in[8];
    const float* lnb_b = (const float*)d_in[9];
    const float* W_b   = (const float*)d_in[10];
    const float* b_b   = (const float*)d_in[11];
    const float* Wg_b  = (const float*)d_in[12];
    const float* bg_b  = (const float*)d_in[13];
    const float* x_c   = (const float*)d_in[14];
    const float* lnw_c = (const float*)d_in[15];
    const float* lnb_c = (const float*)d_in[16];
    const float* W_c   = (const float*)d_in[17];
    const float* b_c   = (const float*)d_in[18];
    const float* Wg_c  = (const float*)d_in[19];
    const float* bg_c  = (const float*)d_in[20];

    // Workspace layout (total ~667 MB)
    char* ws = (char*)d_ws;
    ushort_t* F    = (ushort_t*)ws;                                   // 32768*3584*2
    ushort_t* WT   = (ushort_t*)(ws + 234881024);                     // 4096*3584*2
    ushort_t* Cbuf = (ushort_t*)(ws + 234881024 + 29360128);          // 32768*6144*2
    float*    bias = (float*)   (ws + 234881024 + 29360128 + 402653184); // 6144*4

    hipLaunchKernelGGL(pack_wt_kernel, dim3(2048, 3), dim3(256), 0, stream,
                       W_a, Wg_a, W_b, Wg_b, W_c, Wg_c, WT);
    hipLaunchKernelGGL(pack_bias_kernel, dim3(24), dim3(256), 0, stream,
                       b_a, b_b, b_c, bg_a, bg_b, bg_c, bias);
    hipLaunchKernelGGL(ln_relu_kernel, dim3(32768, 3), dim3(256), 0, stream,
                       x_a, x_b, x_c, lnw_a, lnw_b, lnw_c, lnb_a, lnb_b, lnb_c, F);
    hipLaunchKernelGGL(gemm_kernel, dim3(3072), dim3(512), 131072, stream,
                       F, WT, bias, Cbuf);
    hipLaunchKernelGGL(fuse_kernel, dim3(16384), dim3(256), 0, stream,
                       Cbuf, (float*)d_out);
}